// Round 2
// baseline (930.088 us; speedup 1.0000x reference)
//
#include <hip/hip_runtime.h>

#define D 768
#define B 32
#define L 512
#define M 128
#define NNODES 3072
#define NEDGES 24576

using bf16x8 = __attribute__((ext_vector_type(8))) short;
using f32x4  = __attribute__((ext_vector_type(4))) float;

__device__ __forceinline__ float bf2f(unsigned short u) {
  union { unsigned int i; float f; } v; v.i = ((unsigned int)u) << 16; return v.f;
}
__device__ __forceinline__ unsigned short f2bf(float f) {
  union { float f; unsigned int i; } v; v.f = f;
  unsigned int x = v.i;
  return (unsigned short)((x + 0x7FFFu + ((x >> 16) & 1u)) >> 16);
}
// load float input element i, fp32 or bf16 per flag
__device__ __forceinline__ float ldf(const void* p, size_t i, int f32) {
  return f32 ? ((const float*)p)[i] : bf2f(((const unsigned short*)p)[i]);
}
// load integer input element i, int64 or int32 per flag
__device__ __forceinline__ int ldi(const void* p, size_t i, int w64) {
  return w64 ? (int)((const long long*)p)[i] : ((const int*)p)[i];
}
__device__ __forceinline__ f32x4 mfma16(bf16x8 a, bf16x8 b, f32x4 c) {
  return __builtin_amdgcn_mfma_f32_16x16x32_bf16(a, b, c, 0, 0, 0);
}

// ---------- dtype detection: flags[0]=floats-are-fp32, flags[1]=ints-are-64bit ----------
__global__ void k_detect(const unsigned short* __restrict__ t,
                         const unsigned int* __restrict__ e, int* __restrict__ flags) {
  __shared__ int r0[256];
  __shared__ unsigned r1[256];
  int tid = threadIdx.x;
  int bad = 0;
  // even ushorts = fp32 low mantissa halves if fp32; bf16 N(0,1) never has exp>=0xC0
  for (int i = tid; i < 8192; i += 256) {
    unsigned short u = t[2 * i];
    unsigned ex = (u >> 7) & 0xFF;
    if (ex >= 0xC0) bad = 1;
  }
  unsigned o = 0;
  // odd 32-bit words: all-zero iff int64 (high words of node ids < 2^31)
  for (int i = tid; i < NEDGES / 2; i += 256) o |= e[2 * i + 1];
  r0[tid] = bad; r1[tid] = o;
  __syncthreads();
  for (int s = 128; s > 0; s >>= 1) {
    if (tid < s) { r0[tid] |= r0[tid + s]; r1[tid] |= r1[tid + s]; }
    __syncthreads();
  }
  if (tid == 0) { flags[0] = r0[0]; flags[1] = (r1[0] == 0) ? 1 : 0; }
}

// convert float input -> canonical bf16 (pure copy skipped if already bf16 and skip_if_bf16)
__global__ void k_cvt(const void* __restrict__ src, unsigned short* __restrict__ dst,
                      int n, const int* __restrict__ flags, int skip_if_bf16) {
  int f = flags[0];
  if (!f && skip_if_bf16) return;
  int i = blockIdx.x * 256 + threadIdx.x;
  if (i >= n) return;
  dst[i] = f ? f2bf(((const float*)src)[i]) : ((const unsigned short*)src)[i];
}

// ---------------- setup kernels ----------------

__global__ void k_init(int* cnt, int* cursor, int* gcnt, float* pooled) {
  int i = blockIdx.x * 256 + threadIdx.x;
  if (i < NNODES) { cnt[i] = 0; cursor[i] = 0; }
  if (i < B) gcnt[i] = 0;
  if (i < B * D) pooled[i] = 0.f;
}

__global__ void k_count(const void* __restrict__ edst, const void* __restrict__ batch,
                        const int* __restrict__ flags, int* __restrict__ cnt,
                        int* __restrict__ gcnt) {
  int w = flags[1];
  int i = blockIdx.x * 256 + threadIdx.x;
  if (i < NEDGES) atomicAdd(&cnt[ldi(edst, i, w)], 1);
  if (i < NNODES) atomicAdd(&gcnt[ldi(batch, i, w)], 1);
}

// exclusive scan of cnt[0..3071] -> rowstart[0..3072], single block 1024 threads
__global__ void k_scan(const int* __restrict__ cnt, int* __restrict__ rowstart) {
  __shared__ int a[NNODES], b[NNODES];
  int tid = threadIdx.x;
  for (int i = tid; i < NNODES; i += 1024) a[i] = cnt[i];
  __syncthreads();
  int* s = a; int* d = b;
  for (int off = 1; off < NNODES; off <<= 1) {
    for (int i = tid; i < NNODES; i += 1024)
      d[i] = s[i] + (i >= off ? s[i - off] : 0);
    __syncthreads();
    int* t = s; s = d; d = t;
  }
  for (int i = tid; i < NNODES; i += 1024) rowstart[i + 1] = s[i];
  if (tid == 0) rowstart[0] = 0;
}

__global__ void k_scatter(const void* __restrict__ esrc, const void* __restrict__ edst,
                          const int* __restrict__ flags, const int* __restrict__ rowstart,
                          int* __restrict__ cursor, int* __restrict__ csr) {
  int w = flags[1];
  int i = blockIdx.x * 256 + threadIdx.x;
  if (i < NEDGES) {
    int dd = ldi(edst, i, w);
    int pos = atomicAdd(&cursor[dd], 1);
    csr[rowstart[dd] + pos] = ldi(esrc, i, w);
  }
}

// transpose gnn weights into bf16: WT[n][k] = W[k][n], 6 matrices (3 ws + 3 wn)
__global__ void k_transpose(const void* __restrict__ Ws, const void* __restrict__ Wn,
                            const int* __restrict__ flags,
                            unsigned short* __restrict__ WsT,
                            unsigned short* __restrict__ WnT) {
  __shared__ unsigned short tile[32][33];
  int f = flags[0];
  int z = blockIdx.z;
  const void* src = (z < 3) ? Ws : Wn;
  size_t zoff = (size_t)((z < 3) ? z : z - 3) * D * D;
  unsigned short* dst = ((z < 3) ? WsT : WnT) + zoff;
  int k0 = blockIdx.x * 32, n0 = blockIdx.y * 32;
  int tx = threadIdx.x, ty = threadIdx.y;
#pragma unroll
  for (int j = 0; j < 4; ++j)
    tile[ty + j * 8][tx] = f2bf(ldf(src, zoff + (size_t)(k0 + ty + j * 8) * D + n0 + tx, f));
  __syncthreads();
#pragma unroll
  for (int j = 0; j < 4; ++j)
    dst[(size_t)(n0 + ty + j * 8) * D + k0 + tx] = tile[tx][ty + j * 8];
}

// ---------------- per-layer kernels ----------------

// msg[n] = mean over in-edges of x[src]
__global__ void k_msg(const unsigned short* __restrict__ x, const int* __restrict__ cnt,
                      const int* __restrict__ rowstart, const int* __restrict__ csr,
                      unsigned short* __restrict__ msg) {
  int n = blockIdx.x;
  int deg = cnt[n];
  int base = rowstart[n];
  float inv = 1.0f / (float)(deg > 1 ? deg : 1);
  int tid = threadIdx.x;
  float a0 = 0.f, a1 = 0.f, a2 = 0.f;
  for (int e = 0; e < deg; ++e) {
    const unsigned short* xr = x + (size_t)csr[base + e] * D;
    a0 += bf2f(xr[tid]);
    a1 += bf2f(xr[tid + 256]);
    a2 += bf2f(xr[tid + 512]);
  }
  unsigned short* mr = msg + (size_t)n * D;
  mr[tid]       = f2bf(a0 * inv);
  mr[tid + 256] = f2bf(a1 * inv);
  mr[tid + 512] = f2bf(a2 * inv);
}

// Y = relu([X|MSG] @ [WsT;WnT]^T + bias), 3072x768, K=1536. Block 64x128, wave 32x64.
__global__ __launch_bounds__(256) void k_gemm_gnn(
    const unsigned short* __restrict__ X, const unsigned short* __restrict__ MSG,
    const unsigned short* __restrict__ WsT, const unsigned short* __restrict__ WnT,
    const void* __restrict__ bias, size_t bias_off, const int* __restrict__ flags,
    unsigned short* __restrict__ Y) {
  int f = flags[0];
  int tid = threadIdx.x;
  int wave = tid >> 6, lane = tid & 63;
  int q = lane >> 4, t = lane & 15;
  int m0 = blockIdx.x * 64 + (wave >> 1) * 32;
  int n0 = blockIdx.y * 128 + (wave & 1) * 64;
  f32x4 acc[2][4];
#pragma unroll
  for (int mi = 0; mi < 2; ++mi)
#pragma unroll
    for (int ni = 0; ni < 4; ++ni)
      acc[mi][ni] = (f32x4){0.f, 0.f, 0.f, 0.f};
#pragma unroll
  for (int half = 0; half < 2; ++half) {
    const unsigned short* Ab = half ? MSG : X;
    const unsigned short* Wb = half ? WnT : WsT;
    for (int kk = 0; kk < D; kk += 32) {
      bf16x8 a0 = *(const bf16x8*)(Ab + (size_t)(m0 + t) * D + kk + q * 8);
      bf16x8 a1 = *(const bf16x8*)(Ab + (size_t)(m0 + 16 + t) * D + kk + q * 8);
#pragma unroll
      for (int ni = 0; ni < 4; ++ni) {
        bf16x8 bv = *(const bf16x8*)(Wb + (size_t)(n0 + ni * 16 + t) * D + kk + q * 8);
        acc[0][ni] = mfma16(a0, bv, acc[0][ni]);
        acc[1][ni] = mfma16(a1, bv, acc[1][ni]);
      }
    }
  }
#pragma unroll
  for (int ni = 0; ni < 4; ++ni) {
    int col = n0 + ni * 16 + t;
    float bv = ldf(bias, bias_off + col, f);
#pragma unroll
    for (int mi = 0; mi < 2; ++mi) {
#pragma unroll
      for (int r = 0; r < 4; ++r) {
        int row = m0 + mi * 16 + q * 4 + r;
        float v = acc[mi][ni][r] + bv;
        Y[(size_t)row * D + col] = f2bf(v > 0.f ? v : 0.f);
      }
    }
  }
}

// xp[b,m] = (m < nb) ? Y[pad_idx[b,m]] : 0
__global__ void k_xp(const unsigned short* __restrict__ Xn, const void* __restrict__ pidx,
                     const int* __restrict__ flags, const int* __restrict__ gcnt,
                     unsigned short* __restrict__ xp) {
  int w = flags[1];
  int bm = blockIdx.x;
  int b = bm >> 7, m = bm & 127;
  int nb = gcnt[b];
  int tid = threadIdx.x;
  unsigned short* dst = xp + (size_t)bm * D;
  if (m < nb) {
    const unsigned short* srcr = Xn + (size_t)ldi(pidx, bm, w) * D;
    dst[tid] = srcr[tid];
    dst[tid + 256] = srcr[tid + 256];
    dst[tid + 512] = srcr[tid + 512];
  } else {
    dst[tid] = 0; dst[tid + 256] = 0; dst[tid + 512] = 0;
  }
}

// S[b] = xp[b] @ text[b]^T  (128x512, K=768), fp32 out. Block 64x128, wave 32x64.
__global__ __launch_bounds__(256) void k_scores(
    const unsigned short* __restrict__ xp, const unsigned short* __restrict__ traw,
    const unsigned short* __restrict__ tcvt, const int* __restrict__ flags,
    float* __restrict__ S) {
  const unsigned short* text = flags[0] ? tcvt : traw;
  int b = blockIdx.y;
  int mt = blockIdx.x >> 2, lt = blockIdx.x & 3;
  int tid = threadIdx.x;
  int wave = tid >> 6, lane = tid & 63;
  int q = lane >> 4, t = lane & 15;
  int m0 = mt * 64 + (wave >> 1) * 32;
  int l0 = lt * 128 + (wave & 1) * 64;
  const unsigned short* Xb = xp + (size_t)b * M * D;
  const unsigned short* Tb = text + (size_t)b * L * D;
  f32x4 acc[2][4];
#pragma unroll
  for (int mi = 0; mi < 2; ++mi)
#pragma unroll
    for (int ni = 0; ni < 4; ++ni)
      acc[mi][ni] = (f32x4){0.f, 0.f, 0.f, 0.f};
  for (int kk = 0; kk < D; kk += 32) {
    bf16x8 a0 = *(const bf16x8*)(Xb + (size_t)(m0 + t) * D + kk + q * 8);
    bf16x8 a1 = *(const bf16x8*)(Xb + (size_t)(m0 + 16 + t) * D + kk + q * 8);
#pragma unroll
    for (int ni = 0; ni < 4; ++ni) {
      bf16x8 bv = *(const bf16x8*)(Tb + (size_t)(l0 + ni * 16 + t) * D + kk + q * 8);
      acc[0][ni] = mfma16(a0, bv, acc[0][ni]);
      acc[1][ni] = mfma16(a1, bv, acc[1][ni]);
    }
  }
  float* Sb = S + (size_t)b * M * L;
#pragma unroll
  for (int ni = 0; ni < 4; ++ni) {
    int col = l0 + ni * 16 + t;
#pragma unroll
    for (int mi = 0; mi < 2; ++mi) {
#pragma unroll
      for (int r = 0; r < 4; ++r) {
        int row = m0 + mi * 16 + q * 4 + r;
        Sb[(size_t)row * L + col] = acc[mi][ni][r];
      }
    }
  }
}

// per (b,m): row max + sum(exp) over l
__global__ __launch_bounds__(256) void k_rowstat(const float* __restrict__ S,
                                                 float* __restrict__ rmax, float* __restrict__ rsum) {
  __shared__ float red[4];
  int row = blockIdx.x, tid = threadIdx.x;
  int lane = tid & 63, wv = tid >> 6;
  const float* r = S + (size_t)row * L;
  float s0 = r[tid], s1 = r[tid + 256];
  float m = fmaxf(s0, s1);
#pragma unroll
  for (int o = 32; o > 0; o >>= 1) m = fmaxf(m, __shfl_down(m, o));
  if (lane == 0) red[wv] = m;
  __syncthreads();
  float bm = fmaxf(fmaxf(red[0], red[1]), fmaxf(red[2], red[3]));
  __syncthreads();
  float e = __expf(s0 - bm) + __expf(s1 - bm);
#pragma unroll
  for (int o = 32; o > 0; o >>= 1) e += __shfl_down(e, o);
  if (lane == 0) red[wv] = e;
  __syncthreads();
  if (tid == 0) { rmax[row] = bm; rsum[row] = red[0] + red[1] + red[2] + red[3]; }
}

// per (b,l): w = sum_m g2t, cmax/csum for t2g softmax over valid m
__global__ __launch_bounds__(128) void k_colstat(
    const float* __restrict__ S, const float* __restrict__ rmax, const float* __restrict__ rsum,
    const int* __restrict__ gcnt, float* __restrict__ wv, float* __restrict__ cmaxv,
    float* __restrict__ csumv) {
  __shared__ float rm[M], ri[M];
  int b = blockIdx.x, tid = threadIdx.x;
  rm[tid] = rmax[b * M + tid];
  ri[tid] = 1.f / rsum[b * M + tid];
  __syncthreads();
  int l = blockIdx.y * 128 + tid;
  int nb = gcnt[b];
  const float* Sb = S + (size_t)b * M * L;
  float w = 0.f, cm = -1e30f;
  for (int m = 0; m < nb; ++m) {
    float s = Sb[(size_t)m * L + l];
    w += __expf(s - rm[m]) * ri[m];
    cm = fmaxf(cm, s);
  }
  float cs = 0.f;
  for (int m = 0; m < nb; ++m) {
    float s = Sb[(size_t)m * L + l];
    cs += __expf(s - cm);
  }
  wv[b * L + l] = w;
  cmaxv[b * L + l] = cm;
  csumv[b * L + l] = cs;
}

// per (b,m): t2gcol = sum_l t2g[b,l,m]
__global__ __launch_bounds__(256) void k_colsum(
    const float* __restrict__ S, const float* __restrict__ cmaxv, const float* __restrict__ csumv,
    const int* __restrict__ gcnt, float* __restrict__ t2gcol) {
  __shared__ float red[4];
  int bm = blockIdx.x, tid = threadIdx.x;
  int b = bm >> 7, m = bm & 127;
  int lane = tid & 63, wv_ = tid >> 6;
  int nb = gcnt[b];
  float acc = 0.f;
  if (m < nb) {
    const float* r = S + (size_t)bm * L;
    const float* cm = cmaxv + b * L;
    const float* cs = csumv + b * L;
    acc = __expf(r[tid] - cm[tid]) / cs[tid]
        + __expf(r[tid + 256] - cm[tid + 256]) / cs[tid + 256];
  }
#pragma unroll
  for (int o = 32; o > 0; o >>= 1) acc += __shfl_down(acc, o);
  if (lane == 0) red[wv_] = acc;
  __syncthreads();
  if (tid == 0) t2gcol[bm] = red[0] + red[1] + red[2] + red[3];
}

// pooled[b,d] += (sum_l w[b,l]*text[b,l,d] + sum_m t2gcol[b,m]*xp[b,m,d]) / (nb+L)
__global__ __launch_bounds__(256) void k_pooled(
    const float* __restrict__ wv, const float* __restrict__ t2gcol,
    const unsigned short* __restrict__ traw, const unsigned short* __restrict__ tcvt,
    const int* __restrict__ flags, const unsigned short* __restrict__ xp,
    const int* __restrict__ gcnt, float* __restrict__ pooled) {
  const unsigned short* text = flags[0] ? tcvt : traw;
  int b = blockIdx.x;
  int d = blockIdx.y * 256 + threadIdx.x;
  const unsigned short* Tb = text + (size_t)b * L * D;
  const unsigned short* Xb = xp + (size_t)b * M * D;
  float acc = 0.f;
  for (int l = 0; l < L; ++l) acc += wv[b * L + l] * bf2f(Tb[(size_t)l * D + d]);
  for (int m = 0; m < M; ++m) acc += t2gcol[b * M + m] * bf2f(Xb[(size_t)m * D + d]);
  pooled[(size_t)b * D + d] += acc / ((float)gcnt[b] + 512.f);
}

// ---------------- final assembly ----------------
__global__ __launch_bounds__(256) void k_final(
    const unsigned short* __restrict__ traw, const unsigned short* __restrict__ tcvt,
    const unsigned short* __restrict__ xp, const float* __restrict__ pooled,
    const void* __restrict__ aw, const void* __restrict__ ab,
    const void* __restrict__ dmask, const void* __restrict__ gmask,
    const void* __restrict__ remb, const int* __restrict__ gcnt,
    const int* __restrict__ flags, void* __restrict__ out) {
  __shared__ float xg[D];
  int f = flags[0];
  const unsigned short* text = f ? tcvt : traw;
  int b = blockIdx.x, tid = threadIdx.x;
  float dm = ldf(dmask, b, f);
  float gm = ldf(gmask, b, f);
  float dg = dm * gm;
  int nb = gcnt[b];
  float invnb = 1.0f / (float)(nb > 1 ? nb : 1);
  const unsigned short* Xb = xp + (size_t)b * M * D;
#pragma unroll
  for (int j = 0; j < 3; ++j) {
    int d = tid + j * 256;
    float s = 0.f;
    for (int m = 0; m < M; ++m) s += bf2f(Xb[(size_t)m * D + d]);
    xg[d] = s * invnb;
  }
  __syncthreads();
  float g0 = 0.f, g1 = 0.f, g2 = 0.f;
  for (int k = 0; k < D; ++k) {
    float xv = xg[k];
    size_t ro = (size_t)k * D;
    g0 += xv * ldf(aw, ro + tid, f);
    g1 += xv * ldf(aw, ro + tid + 256, f);
    g2 += xv * ldf(aw, ro + tid + 512, f);
  }
  float gacc[3] = {g0, g1, g2};
  size_t base = (size_t)b * 2304;
#pragma unroll
  for (int j = 0; j < 3; ++j) {
    int d = tid + j * 256;
    float z = ldf(remb, d, f);
    float tv = bf2f(text[(size_t)b * L * D + d]);
    float o0 = tv * dm + (1.f - dm) * z;
    float gv = tanhf(gacc[j] + ldf(ab, d, f));
    float o1 = gv * gm + (1.f - gm) * z;
    float p = pooled[(size_t)b * D + d] * (1.f / 3.f);
    float o2 = p * dg + (1.f - dg) * z;
    if (f) {
      float* of = (float*)out;
      of[base + d] = o0; of[base + 768 + d] = o1; of[base + 1536 + d] = o2;
    } else {
      unsigned short* ob = (unsigned short*)out;
      ob[base + d] = f2bf(o0); ob[base + 768 + d] = f2bf(o1); ob[base + 1536 + d] = f2bf(o2);
    }
  }
}

extern "C" void kernel_launch(void* const* d_in, const int* in_sizes, int n_in,
                              void* d_out, int out_size, void* d_ws, size_t ws_size,
                              hipStream_t stream) {
  const void* x_in  = d_in[0];
  const void* text  = d_in[1];
  const void* dmask = d_in[2];
  const void* gmask = d_in[3];
  const void* gws   = d_in[4];
  const void* gwn   = d_in[5];
  const void* gb    = d_in[6];
  const void* aw    = d_in[7];
  const void* ab    = d_in[8];
  const void* remb  = d_in[9];
  const void* batch = d_in[10];
  const void* pidx  = d_in[11];
  // d_in[12] = pad_mask — unused; mask derived from batch counts
  const void* esrc  = d_in[13];
  const void* edst  = d_in[14];

  char* wsp = (char*)d_ws;
  size_t off = 0;
  auto carve = [&](size_t bytes) -> void* {
    void* p = wsp + off;
    off += (bytes + 255) & ~(size_t)255;
    return p;
  };
  int* flags = (int*)carve(2 * 4);
  unsigned short* x0    = (unsigned short*)carve((size_t)NNODES * D * 2);
  unsigned short* xA    = (unsigned short*)carve((size_t)NNODES * D * 2);
  unsigned short* xB    = (unsigned short*)carve((size_t)NNODES * D * 2);
  unsigned short* msg   = (unsigned short*)carve((size_t)NNODES * D * 2);
  unsigned short* textb = (unsigned short*)carve((size_t)B * L * D * 2);
  unsigned short* WsT   = (unsigned short*)carve((size_t)3 * D * D * 2);
  unsigned short* WnT   = (unsigned short*)carve((size_t)3 * D * D * 2);
  unsigned short* xp    = (unsigned short*)carve((size_t)B * M * D * 2);
  float* S       = (float*)carve((size_t)B * M * L * 4);
  float* rmax    = (float*)carve((size_t)B * M * 4);
  float* rsum    = (float*)carve((size_t)B * M * 4);
  float* wv      = (float*)carve((size_t)B * L * 4);
  float* cmaxv   = (float*)carve((size_t)B * L * 4);
  float* csumv   = (float*)carve((size_t)B * L * 4);
  float* t2gcol  = (float*)carve((size_t)B * M * 4);
  float* pooled  = (float*)carve((size_t)B * D * 4);
  int* cnt      = (int*)carve((size_t)NNODES * 4);
  int* rowstart = (int*)carve((size_t)(NNODES + 1) * 4);
  int* cursor   = (int*)carve((size_t)NNODES * 4);
  int* gcnt     = (int*)carve((size_t)B * 4);
  int* csr      = (int*)carve((size_t)NEDGES * 4);

  k_detect<<<1, 256, 0, stream>>>((const unsigned short*)text, (const unsigned int*)edst, flags);
  k_init<<<96, 256, 0, stream>>>(cnt, cursor, gcnt, pooled);
  // x0 always converted (cheap, 4.7MB); textb conversion early-outs if already bf16
  k_cvt<<<(NNODES * D + 255) / 256, 256, 0, stream>>>(x_in, x0, NNODES * D, flags, 0);
  k_cvt<<<(B * L * D + 255) / 256, 256, 0, stream>>>(text, textb, B * L * D, flags, 1);
  k_transpose<<<dim3(24, 24, 6), dim3(32, 8), 0, stream>>>(gws, gwn, flags, WsT, WnT);
  k_count<<<96, 256, 0, stream>>>(edst, batch, flags, cnt, gcnt);
  k_scan<<<1, 1024, 0, stream>>>(cnt, rowstart);
  k_scatter<<<96, 256, 0, stream>>>(esrc, edst, flags, rowstart, cursor, csr);

  const unsigned short* traw = (const unsigned short*)text;
  const unsigned short* xsrc = x0;
  unsigned short* xdst = xA;
  for (int i = 0; i < 3; ++i) {
    k_msg<<<NNODES, 256, 0, stream>>>(xsrc, cnt, rowstart, csr, msg);
    k_gemm_gnn<<<dim3(48, 6), 256, 0, stream>>>(xsrc, msg, WsT + (size_t)i * D * D,
                                                WnT + (size_t)i * D * D, gb, (size_t)i * D,
                                                flags, xdst);
    k_xp<<<B * M, 256, 0, stream>>>(xdst, pidx, flags, gcnt, xp);
    k_scores<<<dim3(8, B), 256, 0, stream>>>(xp, traw, textb, flags, S);
    k_rowstat<<<B * M, 256, 0, stream>>>(S, rmax, rsum);
    k_colstat<<<dim3(B, 4), 128, 0, stream>>>(S, rmax, rsum, gcnt, wv, cmaxv, csumv);
    k_colsum<<<B * M, 256, 0, stream>>>(S, cmaxv, csumv, gcnt, t2gcol);
    k_pooled<<<dim3(B, 3), 256, 0, stream>>>(wv, t2gcol, traw, textb, flags, xp, gcnt, pooled);
    xsrc = xdst;
    xdst = (i == 0) ? xB : xA;
  }
  k_final<<<B, 256, 0, stream>>>(traw, textb, xp, pooled, aw, ab, dmask, gmask, remb,
                                 gcnt, flags, d_out);
}

// Round 3
// 616.068 us; speedup vs baseline: 1.5097x; 1.5097x over previous
//
#include <hip/hip_runtime.h>

#define D 768
#define B 32
#define L 512
#define M 128
#define NNODES 3072
#define NEDGES 24576

using bf16x8 = __attribute__((ext_vector_type(8))) short;
using f32x4  = __attribute__((ext_vector_type(4))) float;

__device__ __forceinline__ float bf2f(unsigned short u) {
  union { unsigned int i; float f; } v; v.i = ((unsigned int)u) << 16; return v.f;
}
__device__ __forceinline__ unsigned short f2bf(float f) {
  union { float f; unsigned int i; } v; v.f = f;
  unsigned int x = v.i;
  return (unsigned short)((x + 0x7FFFu + ((x >> 16) & 1u)) >> 16);
}
__device__ __forceinline__ float ldf(const void* p, size_t i, int f32) {
  return f32 ? ((const float*)p)[i] : bf2f(((const unsigned short*)p)[i]);
}
__device__ __forceinline__ int ldi(const void* p, size_t i, int w64) {
  return w64 ? (int)((const long long*)p)[i] : ((const int*)p)[i];
}
__device__ __forceinline__ f32x4 mfma16(bf16x8 a, bf16x8 b, f32x4 c) {
  return __builtin_amdgcn_mfma_f32_16x16x32_bf16(a, b, c, 0, 0, 0);
}

// ---------- dtype detection: flags[0]=floats-are-fp32, flags[1]=ints-are-64bit ----------
__global__ void k_detect(const unsigned short* __restrict__ t,
                         const unsigned int* __restrict__ e, int* __restrict__ flags) {
  __shared__ int r0[256];
  __shared__ unsigned r1[256];
  int tid = threadIdx.x;
  int bad = 0;
  for (int i = tid; i < 8192; i += 256) {
    unsigned short u = t[2 * i];
    unsigned ex = (u >> 7) & 0xFF;
    if (ex >= 0xC0) bad = 1;
  }
  unsigned o = 0;
  for (int i = tid; i < NEDGES / 2; i += 256) o |= e[2 * i + 1];
  r0[tid] = bad; r1[tid] = o;
  __syncthreads();
  for (int s = 128; s > 0; s >>= 1) {
    if (tid < s) { r0[tid] |= r0[tid + s]; r1[tid] |= r1[tid + s]; }
    __syncthreads();
  }
  if (tid == 0) { flags[0] = r0[0]; flags[1] = (r1[0] == 0) ? 1 : 0; }
}

__global__ void k_cvt(const void* __restrict__ src, unsigned short* __restrict__ dst,
                      int n, const int* __restrict__ flags, int skip_if_bf16) {
  int f = flags[0];
  if (!f && skip_if_bf16) return;
  int i = blockIdx.x * 256 + threadIdx.x;
  if (i >= n) return;
  dst[i] = f ? f2bf(((const float*)src)[i]) : ((const unsigned short*)src)[i];
}

// ---------------- setup kernels ----------------

__global__ void k_init(int* cnt, int* cursor, int* gcnt, float* pooled) {
  int i = blockIdx.x * 256 + threadIdx.x;
  if (i < NNODES) { cnt[i] = 0; cursor[i] = 0; }
  if (i < B) gcnt[i] = 0;
  if (i < B * D) pooled[i] = 0.f;
}

__global__ void k_count(const void* __restrict__ edst, const void* __restrict__ batch,
                        const int* __restrict__ flags, int* __restrict__ cnt,
                        int* __restrict__ gcnt) {
  int w = flags[1];
  int i = blockIdx.x * 256 + threadIdx.x;
  if (i < NEDGES) atomicAdd(&cnt[ldi(edst, i, w)], 1);
  if (i < NNODES) atomicAdd(&gcnt[ldi(batch, i, w)], 1);
}

__global__ void k_scan(const int* __restrict__ cnt, int* __restrict__ rowstart) {
  __shared__ int a[NNODES], b[NNODES];
  int tid = threadIdx.x;
  for (int i = tid; i < NNODES; i += 1024) a[i] = cnt[i];
  __syncthreads();
  int* s = a; int* d = b;
  for (int off = 1; off < NNODES; off <<= 1) {
    for (int i = tid; i < NNODES; i += 1024)
      d[i] = s[i] + (i >= off ? s[i - off] : 0);
    __syncthreads();
    int* t = s; s = d; d = t;
  }
  for (int i = tid; i < NNODES; i += 1024) rowstart[i + 1] = s[i];
  if (tid == 0) rowstart[0] = 0;
}

__global__ void k_scatter(const void* __restrict__ esrc, const void* __restrict__ edst,
                          const int* __restrict__ flags, const int* __restrict__ rowstart,
                          int* __restrict__ cursor, int* __restrict__ csr) {
  int w = flags[1];
  int i = blockIdx.x * 256 + threadIdx.x;
  if (i < NEDGES) {
    int dd = ldi(edst, i, w);
    int pos = atomicAdd(&cursor[dd], 1);
    csr[rowstart[dd] + pos] = ldi(esrc, i, w);
  }
}

// transpose weights into bf16: z<3 -> WsT, z<6 -> WnT, z==6 -> awT
__global__ void k_transpose(const void* __restrict__ Ws, const void* __restrict__ Wn,
                            const void* __restrict__ Aw, const int* __restrict__ flags,
                            unsigned short* __restrict__ WsT,
                            unsigned short* __restrict__ WnT,
                            unsigned short* __restrict__ AwT) {
  __shared__ unsigned short tile[32][33];
  int f = flags[0];
  int z = blockIdx.z;
  const void* src; unsigned short* dst; size_t zoff;
  if (z < 3)      { src = Ws; zoff = (size_t)z * D * D;       dst = WsT + zoff; }
  else if (z < 6) { src = Wn; zoff = (size_t)(z - 3) * D * D; dst = WnT + zoff; }
  else            { src = Aw; zoff = 0;                       dst = AwT; }
  int k0 = blockIdx.x * 32, n0 = blockIdx.y * 32;
  int tx = threadIdx.x, ty = threadIdx.y;
#pragma unroll
  for (int j = 0; j < 4; ++j)
    tile[ty + j * 8][tx] = f2bf(ldf(src, zoff + (size_t)(k0 + ty + j * 8) * D + n0 + tx, f));
  __syncthreads();
#pragma unroll
  for (int j = 0; j < 4; ++j)
    dst[(size_t)(n0 + ty + j * 8) * D + k0 + tx] = tile[tx][ty + j * 8];
}

// ---------------- per-layer kernels ----------------

// msg[n] = mean over in-edges of x[src]; 192 threads, uint2 (4 bf16) per thread
__global__ __launch_bounds__(192) void k_msg(
    const unsigned short* __restrict__ x, const int* __restrict__ cnt,
    const int* __restrict__ rowstart, const int* __restrict__ csr,
    unsigned short* __restrict__ msg) {
  int n = blockIdx.x;
  int deg = cnt[n];
  int base = rowstart[n];
  float inv = 1.0f / (float)(deg > 1 ? deg : 1);
  int tid = threadIdx.x;
  float a0 = 0.f, a1 = 0.f, a2 = 0.f, a3 = 0.f;
  for (int e = 0; e < deg; ++e) {
    const uint2* xr = (const uint2*)(x + (size_t)csr[base + e] * D);
    uint2 v = xr[tid];
    a0 += bf2f((unsigned short)(v.x & 0xFFFFu));
    a1 += bf2f((unsigned short)(v.x >> 16));
    a2 += bf2f((unsigned short)(v.y & 0xFFFFu));
    a3 += bf2f((unsigned short)(v.y >> 16));
  }
  uint2 o;
  o.x = (unsigned)f2bf(a0 * inv) | ((unsigned)f2bf(a1 * inv) << 16);
  o.y = (unsigned)f2bf(a2 * inv) | ((unsigned)f2bf(a3 * inv) << 16);
  ((uint2*)(msg + (size_t)n * D))[tid] = o;
}

// Y = relu([X|MSG] @ [WsT;WnT]^T + bias), 3072x768, K=1536
__global__ __launch_bounds__(256) void k_gemm_gnn(
    const unsigned short* __restrict__ X, const unsigned short* __restrict__ MSG,
    const unsigned short* __restrict__ WsT, const unsigned short* __restrict__ WnT,
    const void* __restrict__ bias, size_t bias_off, const int* __restrict__ flags,
    unsigned short* __restrict__ Y) {
  int f = flags[0];
  int tid = threadIdx.x;
  int wave = tid >> 6, lane = tid & 63;
  int q = lane >> 4, t = lane & 15;
  int m0 = blockIdx.x * 64 + (wave >> 1) * 32;
  int n0 = blockIdx.y * 128 + (wave & 1) * 64;
  f32x4 acc[2][4];
#pragma unroll
  for (int mi = 0; mi < 2; ++mi)
#pragma unroll
    for (int ni = 0; ni < 4; ++ni)
      acc[mi][ni] = (f32x4){0.f, 0.f, 0.f, 0.f};
#pragma unroll
  for (int half = 0; half < 2; ++half) {
    const unsigned short* Ab = half ? MSG : X;
    const unsigned short* Wb = half ? WnT : WsT;
    for (int kk = 0; kk < D; kk += 32) {
      bf16x8 a0 = *(const bf16x8*)(Ab + (size_t)(m0 + t) * D + kk + q * 8);
      bf16x8 a1 = *(const bf16x8*)(Ab + (size_t)(m0 + 16 + t) * D + kk + q * 8);
#pragma unroll
      for (int ni = 0; ni < 4; ++ni) {
        bf16x8 bv = *(const bf16x8*)(Wb + (size_t)(n0 + ni * 16 + t) * D + kk + q * 8);
        acc[0][ni] = mfma16(a0, bv, acc[0][ni]);
        acc[1][ni] = mfma16(a1, bv, acc[1][ni]);
      }
    }
  }
#pragma unroll
  for (int ni = 0; ni < 4; ++ni) {
    int col = n0 + ni * 16 + t;
    float bv = ldf(bias, bias_off + col, f);
#pragma unroll
    for (int mi = 0; mi < 2; ++mi) {
#pragma unroll
      for (int r = 0; r < 4; ++r) {
        int row = m0 + mi * 16 + q * 4 + r;
        float v = acc[mi][ni][r] + bv;
        Y[(size_t)row * D + col] = f2bf(v > 0.f ? v : 0.f);
      }
    }
  }
}

// xp[b,m] = (m < nb) ? Y[pad_idx[b,m]] : 0; 192 threads, uint2 per thread
__global__ __launch_bounds__(192) void k_xp(
    const unsigned short* __restrict__ Xn, const void* __restrict__ pidx,
    const int* __restrict__ flags, const int* __restrict__ gcnt,
    unsigned short* __restrict__ xp) {
  int w = flags[1];
  int bm = blockIdx.x;
  int b = bm >> 7, m = bm & 127;
  int nb = gcnt[b];
  int tid = threadIdx.x;
  uint2* dst = (uint2*)(xp + (size_t)bm * D);
  if (m < nb) {
    const uint2* srcr = (const uint2*)(Xn + (size_t)ldi(pidx, bm, w) * D);
    dst[tid] = srcr[tid];
  } else {
    dst[tid] = (uint2){0u, 0u};
  }
}

// S[b] = xp[b] @ text[b]^T (128x512, K=768), fp32 out
__global__ __launch_bounds__(256) void k_scores(
    const unsigned short* __restrict__ xp, const unsigned short* __restrict__ traw,
    const unsigned short* __restrict__ tcvt, const int* __restrict__ flags,
    float* __restrict__ S) {
  const unsigned short* text = flags[0] ? tcvt : traw;
  int b = blockIdx.y;
  int mt = blockIdx.x >> 2, lt = blockIdx.x & 3;
  int tid = threadIdx.x;
  int wave = tid >> 6, lane = tid & 63;
  int q = lane >> 4, t = lane & 15;
  int m0 = mt * 64 + (wave >> 1) * 32;
  int l0 = lt * 128 + (wave & 1) * 64;
  const unsigned short* Xb = xp + (size_t)b * M * D;
  const unsigned short* Tb = text + (size_t)b * L * D;
  f32x4 acc[2][4];
#pragma unroll
  for (int mi = 0; mi < 2; ++mi)
#pragma unroll
    for (int ni = 0; ni < 4; ++ni)
      acc[mi][ni] = (f32x4){0.f, 0.f, 0.f, 0.f};
  for (int kk = 0; kk < D; kk += 32) {
    bf16x8 a0 = *(const bf16x8*)(Xb + (size_t)(m0 + t) * D + kk + q * 8);
    bf16x8 a1 = *(const bf16x8*)(Xb + (size_t)(m0 + 16 + t) * D + kk + q * 8);
#pragma unroll
    for (int ni = 0; ni < 4; ++ni) {
      bf16x8 bv = *(const bf16x8*)(Tb + (size_t)(l0 + ni * 16 + t) * D + kk + q * 8);
      acc[0][ni] = mfma16(a0, bv, acc[0][ni]);
      acc[1][ni] = mfma16(a1, bv, acc[1][ni]);
    }
  }
  float* Sb = S + (size_t)b * M * L;
#pragma unroll
  for (int ni = 0; ni < 4; ++ni) {
    int col = l0 + ni * 16 + t;
#pragma unroll
    for (int mi = 0; mi < 2; ++mi) {
#pragma unroll
      for (int r = 0; r < 4; ++r) {
        int row = m0 + mi * 16 + q * 4 + r;
        Sb[(size_t)row * L + col] = acc[mi][ni][r];
      }
    }
  }
}

// per (b,m): row max + sum(exp) over l
__global__ __launch_bounds__(256) void k_rowstat(const float* __restrict__ S,
                                                 float* __restrict__ rmax, float* __restrict__ rsum) {
  __shared__ float red[4];
  int row = blockIdx.x, tid = threadIdx.x;
  int lane = tid & 63, wv = tid >> 6;
  const float* r = S + (size_t)row * L;
  float s0 = r[tid], s1 = r[tid + 256];
  float m = fmaxf(s0, s1);
#pragma unroll
  for (int o = 32; o > 0; o >>= 1) m = fmaxf(m, __shfl_down(m, o));
  if (lane == 0) red[wv] = m;
  __syncthreads();
  float bm = fmaxf(fmaxf(red[0], red[1]), fmaxf(red[2], red[3]));
  __syncthreads();
  float e = __expf(s0 - bm) + __expf(s1 - bm);
#pragma unroll
  for (int o = 32; o > 0; o >>= 1) e += __shfl_down(e, o);
  if (lane == 0) red[wv] = e;
  __syncthreads();
  if (tid == 0) { rmax[row] = bm; rsum[row] = red[0] + red[1] + red[2] + red[3]; }
}

// per (b,l): w = sum_m g2t, cmax/csum for t2g — 4 waves own 32-wide m-chunks, LSE-merged
__global__ __launch_bounds__(256) void k_colstat(
    const float* __restrict__ S, const float* __restrict__ rmax, const float* __restrict__ rsum,
    const int* __restrict__ gcnt, float* __restrict__ wv, float* __restrict__ cmaxv,
    float* __restrict__ csumv) {
  __shared__ float rm[M], ri[M];
  __shared__ float pw[4][64], pm[4][64], ps[4][64];
  int b = blockIdx.x, tid = threadIdx.x;
  int w = tid >> 6, lane = tid & 63;
  if (tid < M) { rm[tid] = rmax[b * M + tid]; ri[tid] = 1.f / rsum[b * M + tid]; }
  __syncthreads();
  int l = blockIdx.y * 64 + lane;
  int nb = gcnt[b];
  const float* Sb = S + (size_t)b * M * L;
  int m0 = w * 32;
  int m1 = min(m0 + 32, nb);
  float wp = 0.f, cm = -1e30f, cs = 0.f;
  for (int m = m0; m < m1; ++m) {
    float s = Sb[(size_t)m * L + l];
    wp += __expf(s - rm[m]) * ri[m];
    if (s > cm) { cs = cs * __expf(cm - s) + 1.f; cm = s; }
    else cs += __expf(s - cm);
  }
  pw[w][lane] = wp; pm[w][lane] = cm; ps[w][lane] = cs;
  __syncthreads();
  if (w == 0) {
    float W = 0.f, CM = -1e30f;
#pragma unroll
    for (int j = 0; j < 4; ++j) { W += pw[j][lane]; CM = fmaxf(CM, pm[j][lane]); }
    float CS = 0.f;
#pragma unroll
    for (int j = 0; j < 4; ++j) CS += ps[j][lane] * __expf(pm[j][lane] - CM);
    wv[b * L + l] = W; cmaxv[b * L + l] = CM; csumv[b * L + l] = CS;
  }
}

// per (b,m): t2gcol = sum_l t2g[b,l,m]
__global__ __launch_bounds__(256) void k_colsum(
    const float* __restrict__ S, const float* __restrict__ cmaxv, const float* __restrict__ csumv,
    const int* __restrict__ gcnt, float* __restrict__ t2gcol) {
  __shared__ float red[4];
  int bm = blockIdx.x, tid = threadIdx.x;
  int b = bm >> 7, m = bm & 127;
  int lane = tid & 63, wv_ = tid >> 6;
  int nb = gcnt[b];
  float acc = 0.f;
  if (m < nb) {
    const float* r = S + (size_t)bm * L;
    const float* cm = cmaxv + b * L;
    const float* cs = csumv + b * L;
    acc = __expf(r[tid] - cm[tid]) / cs[tid]
        + __expf(r[tid + 256] - cm[tid + 256]) / cs[tid + 256];
  }
#pragma unroll
  for (int o = 32; o > 0; o >>= 1) acc += __shfl_down(acc, o);
  if (lane == 0) red[wv_] = acc;
  __syncthreads();
  if (tid == 0) t2gcol[bm] = red[0] + red[1] + red[2] + red[3];
}

// pooled[b,d] += chunked GEMV terms / (nb+L); grid (B, 3, 10)
__global__ __launch_bounds__(256) void k_pooled(
    const float* __restrict__ wv, const float* __restrict__ t2gcol,
    const unsigned short* __restrict__ traw, const unsigned short* __restrict__ tcvt,
    const int* __restrict__ flags, const unsigned short* __restrict__ xp,
    const int* __restrict__ gcnt, float* __restrict__ pooled) {
  const unsigned short* text = flags[0] ? tcvt : traw;
  int b = blockIdx.x;
  int d = blockIdx.y * 256 + threadIdx.x;
  int c = blockIdx.z;
  float acc = 0.f;
  if (c < 8) {
    const unsigned short* Tb = text + (size_t)b * L * D;
    int l0 = c * 64;
    for (int l = l0; l < l0 + 64; ++l) acc += wv[b * L + l] * bf2f(Tb[(size_t)l * D + d]);
  } else {
    const unsigned short* Xb = xp + (size_t)b * M * D;
    int mm0 = (c - 8) * 64;
    for (int m = mm0; m < mm0 + 64; ++m) acc += t2gcol[b * M + m] * bf2f(Xb[(size_t)m * D + d]);
  }
  atomicAdd(&pooled[(size_t)b * D + d], acc / ((float)gcnt[b] + 512.f));
}

// ---------------- final-stage kernels ----------------

// xg[b,d] = mean over valid nodes (masked rows of xp are zero)
__global__ __launch_bounds__(256) void k_xg(const unsigned short* __restrict__ xp,
                                            const int* __restrict__ gcnt,
                                            unsigned short* __restrict__ xgb) {
  int b = blockIdx.x;
  int d = blockIdx.y * 256 + threadIdx.x;
  int nb = gcnt[b];
  float inv = 1.0f / (float)(nb > 1 ? nb : 1);
  const unsigned short* Xb = xp + (size_t)b * M * D;
  float s = 0.f;
  for (int m = 0; m < M; ++m) s += bf2f(Xb[(size_t)m * D + d]);
  xgb[(size_t)b * D + d] = f2bf(s * inv);
}

// gpre = xg @ atom_w (32x768, K=768) via MFMA; grid 12 blocks x 4 waves (16 cols each)
__global__ __launch_bounds__(256) void k_atom(const unsigned short* __restrict__ xgb,
                                              const unsigned short* __restrict__ awT,
                                              float* __restrict__ gpre) {
  int tid = threadIdx.x;
  int w = tid >> 6, lane = tid & 63;
  int q = lane >> 4, t = lane & 15;
  int nbase = blockIdx.x * 64 + w * 16;
  f32x4 acc[2];
  acc[0] = (f32x4){0.f, 0.f, 0.f, 0.f};
  acc[1] = (f32x4){0.f, 0.f, 0.f, 0.f};
  for (int kk = 0; kk < D; kk += 32) {
    bf16x8 a0 = *(const bf16x8*)(xgb + (size_t)t * D + kk + q * 8);
    bf16x8 a1 = *(const bf16x8*)(xgb + (size_t)(16 + t) * D + kk + q * 8);
    bf16x8 bv = *(const bf16x8*)(awT + (size_t)(nbase + t) * D + kk + q * 8);
    acc[0] = mfma16(a0, bv, acc[0]);
    acc[1] = mfma16(a1, bv, acc[1]);
  }
#pragma unroll
  for (int mi = 0; mi < 2; ++mi)
#pragma unroll
    for (int r = 0; r < 4; ++r) {
      int row = mi * 16 + q * 4 + r;
      gpre[(size_t)row * D + nbase + t] = acc[mi][r];
    }
}

__global__ __launch_bounds__(256) void k_final(
    const unsigned short* __restrict__ traw, const unsigned short* __restrict__ tcvt,
    const float* __restrict__ gpre, const float* __restrict__ pooled,
    const void* __restrict__ ab, const void* __restrict__ dmask,
    const void* __restrict__ gmask, const void* __restrict__ remb,
    const int* __restrict__ flags, void* __restrict__ out) {
  int f = flags[0];
  const unsigned short* text = f ? tcvt : traw;
  int b = blockIdx.x, tid = threadIdx.x;
  float dm = ldf(dmask, b, f);
  float gm = ldf(gmask, b, f);
  float dg = dm * gm;
  size_t base = (size_t)b * 2304;
#pragma unroll
  for (int j = 0; j < 3; ++j) {
    int d = tid + j * 256;
    float z = ldf(remb, d, f);
    float tv = bf2f(text[(size_t)b * L * D + d]);
    float o0 = tv * dm + (1.f - dm) * z;
    float gv = tanhf(gpre[(size_t)b * D + d] + ldf(ab, d, f));
    float o1 = gv * gm + (1.f - gm) * z;
    float p = pooled[(size_t)b * D + d] * (1.f / 3.f);
    float o2 = p * dg + (1.f - dg) * z;
    if (f) {
      float* of = (float*)out;
      of[base + d] = o0; of[base + 768 + d] = o1; of[base + 1536 + d] = o2;
    } else {
      unsigned short* ob = (unsigned short*)out;
      ob[base + d] = f2bf(o0); ob[base + 768 + d] = f2bf(o1); ob[base + 1536 + d] = f2bf(o2);
    }
  }
}

extern "C" void kernel_launch(void* const* d_in, const int* in_sizes, int n_in,
                              void* d_out, int out_size, void* d_ws, size_t ws_size,
                              hipStream_t stream) {
  const void* x_in  = d_in[0];
  const void* text  = d_in[1];
  const void* dmask = d_in[2];
  const void* gmask = d_in[3];
  const void* gws   = d_in[4];
  const void* gwn   = d_in[5];
  const void* gb    = d_in[6];
  const void* aw    = d_in[7];
  const void* ab    = d_in[8];
  const void* remb  = d_in[9];
  const void* batch = d_in[10];
  const void* pidx  = d_in[11];
  const void* esrc  = d_in[13];
  const void* edst  = d_in[14];

  char* wsp = (char*)d_ws;
  size_t off = 0;
  auto carve = [&](size_t bytes) -> void* {
    void* p = wsp + off;
    off += (bytes + 255) & ~(size_t)255;
    return p;
  };
  int* flags = (int*)carve(2 * 4);
  unsigned short* x0    = (unsigned short*)carve((size_t)NNODES * D * 2);
  unsigned short* xA    = (unsigned short*)carve((size_t)NNODES * D * 2);
  unsigned short* xB    = (unsigned short*)carve((size_t)NNODES * D * 2);
  unsigned short* msg   = (unsigned short*)carve((size_t)NNODES * D * 2);
  unsigned short* textb = (unsigned short*)carve((size_t)B * L * D * 2);
  unsigned short* WsT   = (unsigned short*)carve((size_t)3 * D * D * 2);
  unsigned short* WnT   = (unsigned short*)carve((size_t)3 * D * D * 2);
  unsigned short* AwT   = (unsigned short*)carve((size_t)D * D * 2);
  unsigned short* xp    = (unsigned short*)carve((size_t)B * M * D * 2);
  unsigned short* xgb   = (unsigned short*)carve((size_t)B * D * 2);
  float* gpre    = (float*)carve((size_t)B * D * 4);
  float* S       = (float*)carve((size_t)B * M * L * 4);
  float* rmax    = (float*)carve((size_t)B * M * 4);
  float* rsum    = (float*)carve((size_t)B * M * 4);
  float* wv      = (float*)carve((size_t)B * L * 4);
  float* cmaxv   = (float*)carve((size_t)B * L * 4);
  float* csumv   = (float*)carve((size_t)B * L * 4);
  float* t2gcol  = (float*)carve((size_t)B * M * 4);
  float* pooled  = (float*)carve((size_t)B * D * 4);
  int* cnt      = (int*)carve((size_t)NNODES * 4);
  int* rowstart = (int*)carve((size_t)(NNODES + 1) * 4);
  int* cursor   = (int*)carve((size_t)NNODES * 4);
  int* gcnt     = (int*)carve((size_t)B * 4);
  int* csr      = (int*)carve((size_t)NEDGES * 4);

  k_detect<<<1, 256, 0, stream>>>((const unsigned short*)text, (const unsigned int*)edst, flags);
  k_init<<<96, 256, 0, stream>>>(cnt, cursor, gcnt, pooled);
  k_cvt<<<(NNODES * D + 255) / 256, 256, 0, stream>>>(x_in, x0, NNODES * D, flags, 0);
  k_cvt<<<(B * L * D + 255) / 256, 256, 0, stream>>>(text, textb, B * L * D, flags, 1);
  k_transpose<<<dim3(24, 24, 7), dim3(32, 8), 0, stream>>>(gws, gwn, aw, flags, WsT, WnT, AwT);
  k_count<<<96, 256, 0, stream>>>(edst, batch, flags, cnt, gcnt);
  k_scan<<<1, 1024, 0, stream>>>(cnt, rowstart);
  k_scatter<<<96, 256, 0, stream>>>(esrc, edst, flags, rowstart, cursor, csr);

  const unsigned short* traw = (const unsigned short*)text;
  const unsigned short* xsrc = x0;
  unsigned short* xdst = xA;
  for (int i = 0; i < 3; ++i) {
    k_msg<<<NNODES, 192, 0, stream>>>(xsrc, cnt, rowstart, csr, msg);
    k_gemm_gnn<<<dim3(48, 6), 256, 0, stream>>>(xsrc, msg, WsT + (size_t)i * D * D,
                                                WnT + (size_t)i * D * D, gb, (size_t)i * D,
                                                flags, xdst);
    k_xp<<<B * M, 192, 0, stream>>>(xdst, pidx, flags, gcnt, xp);
    k_scores<<<dim3(8, B), 256, 0, stream>>>(xp, traw, textb, flags, S);
    k_rowstat<<<B * M, 256, 0, stream>>>(S, rmax, rsum);
    k_colstat<<<dim3(B, 8), 256, 0, stream>>>(S, rmax, rsum, gcnt, wv, cmaxv, csumv);
    k_colsum<<<B * M, 256, 0, stream>>>(S, cmaxv, csumv, gcnt, t2gcol);
    k_pooled<<<dim3(B, 3, 10), 256, 0, stream>>>(wv, t2gcol, traw, textb, flags, xp, gcnt, pooled);
    xsrc = xdst;
    xdst = (i == 0) ? xB : xA;
  }
  k_xg<<<dim3(B, 3), 256, 0, stream>>>(xp, gcnt, xgb);
  k_atom<<<12, 256, 0, stream>>>(xgb, AwT, gpre);
  k_final<<<B, 256, 0, stream>>>(traw, textb, gpre, pooled, ab, dmask, gmask, remb,
                                 flags, d_out);
}